// Round 8
// baseline (344.275 us; speedup 1.0000x reference)
//
#include <hip/hip_runtime.h>

// Problem constants: B=8, C=512, Cq=64, W=2048.
#define B_  8
#define C_  512
#define CQ_ 64
#define W_  2048
#define NROW 640   // stacked output rows: 64 q + 64 k + 512 v

typedef __attribute__((ext_vector_type(8))) short  short8;   // 8 bf16 (MFMA A/B frag)
typedef __attribute__((ext_vector_type(4))) float  f32x4;    // MFMA C/D frag
typedef unsigned short ushort;
typedef unsigned long long ull;

// Workspace layout (float slots). Total = 15,007,744 floats = 60.0 MB.
static constexpr size_t OFF_VB  = 0;                                    // V bf16 [B][C][W]
static constexpr size_t OFF_QTH = OFF_VB  + (size_t)B_ * C_ * W_ / 2;   // qT hi bf16 [B][W][64]
static constexpr size_t OFF_QTL = OFF_QTH + (size_t)B_ * W_ * CQ_ / 2;
static constexpr size_t OFF_KTH = OFF_QTL + (size_t)B_ * W_ * CQ_ / 2;
static constexpr size_t OFF_KTL = OFF_KTH + (size_t)B_ * W_ * CQ_ / 2;
static constexpr size_t OFF_XTH = OFF_KTL + (size_t)B_ * W_ * CQ_ / 2;  // xT hi bf16 [B][W][C]
static constexpr size_t OFF_XTL = OFF_XTH + (size_t)B_ * W_ * C_ / 2;
static constexpr size_t OFF_WH  = OFF_XTL + (size_t)B_ * W_ * C_ / 2;   // Wall hi bf16 [640][C]
static constexpr size_t OFF_WL  = OFF_WH  + (size_t)NROW * C_ / 2;      // Wall lo

static __device__ __forceinline__ ushort f2bf(float f) {
    unsigned int u = __builtin_bit_cast(unsigned int, f);
    u += 0x7fffu + ((u >> 16) & 1u);          // round-to-nearest-even
    return (ushort)(u >> 16);
}
static __device__ __forceinline__ float bf2f(ushort h) {
    unsigned int u = ((unsigned int)h) << 16;
    return __builtin_bit_cast(float, u);
}
static __device__ __forceinline__ ull pack4(const ushort* p) {
    return (ull)p[0] | ((ull)p[1] << 16) | ((ull)p[2] << 32) | ((ull)p[3] << 48);
}

// ---------------------------------------------------------------------------
// Kernel 0a: pack Wq/Wk/Wv into stacked [640][512] hi/lo split-bf16.
// ---------------------------------------------------------------------------
__global__ __launch_bounds__(256) void k_wsplit(
    const float* __restrict__ Wq, const float* __restrict__ Wk,
    const float* __restrict__ Wv, ushort* __restrict__ wh, ushort* __restrict__ wl)
{
    const int idx = (blockIdx.x * 256 + threadIdx.x) * 4;   // < 640*512
    const int row = idx >> 9, col = idx & 511;
    const float* src;
    if (row < 64)       src = Wq + (size_t)row * C_ + col;
    else if (row < 128) src = Wk + (size_t)(row - 64) * C_ + col;
    else                src = Wv + (size_t)(row - 128) * C_ + col;
    float4 v = *reinterpret_cast<const float4*>(src);
    float vv[4] = {v.x, v.y, v.z, v.w};
    ushort h[4], lo[4];
    #pragma unroll
    for (int j = 0; j < 4; ++j) {
        h[j]  = f2bf(vv[j]);
        lo[j] = f2bf(vv[j] - bf2f(h[j]));
    }
    *reinterpret_cast<ull*>(wh + idx) = pack4(h);
    *reinterpret_cast<ull*>(wl + idx) = pack4(lo);
}

// ---------------------------------------------------------------------------
// Kernel 0b: transpose x [B][C][W] fp32 -> xT hi/lo bf16 [B][W][C].
// ---------------------------------------------------------------------------
__global__ __launch_bounds__(256) void k_xt(
    const float* __restrict__ x, ushort* __restrict__ xth, ushort* __restrict__ xtl)
{
    const int b = blockIdx.z, c0 = blockIdx.y * 64, w0 = blockIdx.x * 64;
    __shared__ float ts[64][65];
    const int t = threadIdx.x;
    #pragma unroll
    for (int m = 0; m < 4; ++m) {
        int fi = m * 256 + t;
        int c = fi >> 4, c4 = fi & 15;
        float4 v = *reinterpret_cast<const float4*>(x + ((size_t)b * C_ + c0 + c) * W_ + w0 + c4 * 4);
        ts[c][c4 * 4 + 0] = v.x; ts[c][c4 * 4 + 1] = v.y;
        ts[c][c4 * 4 + 2] = v.z; ts[c][c4 * 4 + 3] = v.w;
    }
    __syncthreads();
    #pragma unroll
    for (int m = 0; m < 4; ++m) {
        int w  = m * 16 + (t >> 4);
        int cc = (t & 15) * 4;
        ushort h[4], lo[4];
        #pragma unroll
        for (int j = 0; j < 4; ++j) {
            float v = ts[cc + j][w];
            h[j]  = f2bf(v);
            lo[j] = f2bf(v - bf2f(h[j]));
        }
        size_t base = ((size_t)b * W_ + w0 + w) * C_ + c0 + cc;
        *reinterpret_cast<ull*>(xth + base) = pack4(h);
        *reinterpret_cast<ull*>(xtl + base) = pack4(lo);
    }
}

// ---------------------------------------------------------------------------
// Kernel 1 (PROVEN round 7): projection GEMM via MFMA. Q/K written transposed
// split-bf16 [B][W][64]; V bf16 [B][C][W]. grid: (32, B), 512 thr.
// ---------------------------------------------------------------------------
__global__ __launch_bounds__(512) void k_projm(
    const ushort* __restrict__ wh, const ushort* __restrict__ wl,
    const ushort* __restrict__ xth, const ushort* __restrict__ xtl,
    const float* __restrict__ bq, const float* __restrict__ bk,
    const float* __restrict__ bv,
    ushort* __restrict__ qth, ushort* __restrict__ qtl,
    ushort* __restrict__ kth, ushort* __restrict__ ktl,
    ushort* __restrict__ vb)
{
    const int b = blockIdx.y, w0 = blockIdx.x * 64;
    const int t = threadIdx.x, l = t & 63, wid = t >> 6;
    const int lr = l & 15, lkb = (l >> 4) * 8;

    f32x4 acc[5][4];
    #pragma unroll
    for (int m = 0; m < 5; ++m)
        #pragma unroll
        for (int n = 0; n < 4; ++n) acc[m][n] = (f32x4){0.f, 0.f, 0.f, 0.f};

    const size_t xbase = ((size_t)b * W_ + w0 + lr) * C_ + lkb;

    for (int kc = 0; kc < 16; ++kc) {
        short8 bhf[4], blf[4];
        #pragma unroll
        for (int n = 0; n < 4; ++n) {
            bhf[n] = *reinterpret_cast<const short8*>(xth + xbase + (size_t)n * 16 * C_ + kc * 32);
            blf[n] = *reinterpret_cast<const short8*>(xtl + xbase + (size_t)n * 16 * C_ + kc * 32);
        }
        #pragma unroll
        for (int m = 0; m < 5; ++m) {
            const int arow = (wid + m * 8) * 16 + lr;
            const size_t abase = (size_t)arow * C_ + kc * 32 + lkb;
            short8 ah = *reinterpret_cast<const short8*>(wh + abase);
            #pragma unroll
            for (int n = 0; n < 4; ++n)
                acc[m][n] = __builtin_amdgcn_mfma_f32_16x16x32_bf16(ah, bhf[n], acc[m][n], 0, 0, 0);
            if (m == 0) {   // Q/K group: add lo-plane cross terms
                short8 al = *reinterpret_cast<const short8*>(wl + abase);
                #pragma unroll
                for (int n = 0; n < 4; ++n) {
                    acc[m][n] = __builtin_amdgcn_mfma_f32_16x16x32_bf16(al, bhf[n], acc[m][n], 0, 0, 0);
                    acc[m][n] = __builtin_amdgcn_mfma_f32_16x16x32_bf16(ah, blf[n], acc[m][n], 0, 0, 0);
                }
            }
        }
    }

    // Epilogue. D layout (m89-validated): col = l&15, row = (l>>4)*4 + reg.
    #pragma unroll
    for (int m = 0; m < 5; ++m) {
        const int rbase16 = (wid + m * 8) * 16;
        if (rbase16 < 128) {
            ushort* oh = (rbase16 < 64) ? qth : kth;
            ushort* ol = (rbase16 < 64) ? qtl : ktl;
            const float* bias = (rbase16 < 64) ? bq : bk;
            const int rb = rbase16 & 63;
            #pragma unroll
            for (int n = 0; n < 4; ++n) {
                const int wcol = w0 + n * 16 + lr;
                ushort h4[4], l4[4];
                #pragma unroll
                for (int r = 0; r < 4; ++r) {
                    const int rowl = rb + (l >> 4) * 4 + r;
                    float val = acc[m][n][r] + bias[rowl];
                    h4[r] = f2bf(val);
                    l4[r] = f2bf(val - bf2f(h4[r]));
                }
                size_t base = ((size_t)b * W_ + wcol) * CQ_ + rb + (l >> 4) * 4;
                *reinterpret_cast<ull*>(oh + base) = pack4(h4);
                *reinterpret_cast<ull*>(ol + base) = pack4(l4);
            }
        } else {
            #pragma unroll
            for (int n = 0; n < 4; ++n) {
                const int wcol = w0 + n * 16 + lr;
                #pragma unroll
                for (int r = 0; r < 4; ++r) {
                    const int rl = rbase16 - 128 + (l >> 4) * 4 + r;
                    vb[((size_t)b * C_ + rl) * W_ + wcol] = f2bf(acc[m][n][r] + bv[rl]);
                }
            }
        }
    }
}

// ---------------------------------------------------------------------------
// Kernel 2 (RESTRUCTURED): fused flash attention, producer-consumer.
// grid: 256 blocks 1D (b = blockIdx&7, i-tile = blockIdx>>3), 512 thr = 8 waves.
//  waves 0-3 (producers): QK^T split-bf16 for 16 i-rows each, online softmax,
//    P bf16 -> double-buffered swizzled LDS; K frags register-double-buffered.
//  waves 4-7 (consumers): 128 c each; flag-gated acc rescale; PV MFMA with
//    early-issued V frags; out = gamma*acc/l + x epilogue.
// One barrier per j-tile; producers compute tile jt+1 while consumers PV jt.
// ---------------------------------------------------------------------------
__global__ __launch_bounds__(512, 2) void k_flash(
    const ushort* __restrict__ qth, const ushort* __restrict__ qtl,
    const ushort* __restrict__ kth, const ushort* __restrict__ ktl,
    const ushort* __restrict__ vb,
    const float* __restrict__ x, const float* __restrict__ gamma,
    float* __restrict__ out)
{
    const int b  = blockIdx.x & 7;
    const int i0 = (blockIdx.x >> 3) * 64;
    const int t = threadIdx.x, l = t & 63, wid = t >> 6;
    const int lr = l & 15, lkb = (l >> 4) * 8;

    __shared__ __align__(16) ushort Ps0[64 * 64];   // P buffers (XOR-swizzled)
    __shared__ __align__(16) ushort Ps1[64 * 64];
    __shared__ float sc0[64], sc1[64], l_lds[64];
    __shared__ int   fl0[4], fl1[4];

    if (wid < 4) {
        // ======================= PRODUCERS =======================
        const int ib = wid * 16;
        short8 qh[2], ql[2];
        {
            const size_t qbase = ((size_t)b * W_ + i0 + ib + lr) * CQ_ + lkb;
            #pragma unroll
            for (int kc = 0; kc < 2; ++kc) {
                qh[kc] = *reinterpret_cast<const short8*>(qth + qbase + kc * 32);
                ql[kc] = *reinterpret_cast<const short8*>(qtl + qbase + kc * 32);
            }
        }
        float mrun[4] = {-3.0e38f, -3.0e38f, -3.0e38f, -3.0e38f};
        float lrun[4] = {0.f, 0.f, 0.f, 0.f};

        short8 khA[2][4], klA[2][4], khB[2][4], klB[2][4];

        auto LOADK = [&](short8 kh[2][4], short8 kl[2][4], int tjt) {
            #pragma unroll
            for (int kc = 0; kc < 2; ++kc)
                #pragma unroll
                for (int n = 0; n < 4; ++n) {
                    const size_t ka = ((size_t)b * W_ + tjt * 64 + n * 16 + lr) * CQ_ + kc * 32 + lkb;
                    kh[kc][n] = *reinterpret_cast<const short8*>(kth + ka);
                    kl[kc][n] = *reinterpret_cast<const short8*>(ktl + ka);
                }
        };
        auto QKSTEP = [&](short8 kh[2][4], short8 kl[2][4],
                          ushort* PsX, float* scX, int* flX) {
            f32x4 e[4];
            #pragma unroll
            for (int n = 0; n < 4; ++n) e[n] = (f32x4){0.f, 0.f, 0.f, 0.f};
            #pragma unroll
            for (int kc = 0; kc < 2; ++kc)
                #pragma unroll
                for (int n = 0; n < 4; ++n) {
                    e[n] = __builtin_amdgcn_mfma_f32_16x16x32_bf16(qh[kc], kh[kc][n], e[n], 0, 0, 0);
                    e[n] = __builtin_amdgcn_mfma_f32_16x16x32_bf16(ql[kc], kh[kc][n], e[n], 0, 0, 0);
                    e[n] = __builtin_amdgcn_mfma_f32_16x16x32_bf16(qh[kc], kl[kc][n], e[n], 0, 0, 0);
                }
            float rmax[4];
            #pragma unroll
            for (int r = 0; r < 4; ++r)
                rmax[r] = fmaxf(fmaxf(e[0][r], e[1][r]), fmaxf(e[2][r], e[3][r]));
            #pragma unroll
            for (int off = 1; off <= 8; off <<= 1)
                #pragma unroll
                for (int r = 0; r < 4; ++r)
                    rmax[r] = fmaxf(rmax[r], __shfl_xor(rmax[r], off));
            float scr[4];
            bool upd = false;
            #pragma unroll
            for (int r = 0; r < 4; ++r) {
                const float mnew = fmaxf(mrun[r], rmax[r]);
                scr[r] = __expf(mrun[r] - mnew);
                mrun[r] = mnew;
                upd = upd || (scr[r] != 1.0f);
            }
            float rsum[4] = {0.f, 0.f, 0.f, 0.f};
            #pragma unroll
            for (int n = 0; n < 4; ++n)
                #pragma unroll
                for (int r = 0; r < 4; ++r) {
                    const float p = __expf(e[n][r] - mrun[r]);
                    e[n][r] = p;
                    rsum[r] += p;
                }
            #pragma unroll
            for (int off = 1; off <= 8; off <<= 1)
                #pragma unroll
                for (int r = 0; r < 4; ++r)
                    rsum[r] += __shfl_xor(rsum[r], off);
            #pragma unroll
            for (int r = 0; r < 4; ++r)
                lrun[r] = lrun[r] * scr[r] + rsum[r];
            #pragma unroll
            for (int n = 0; n < 4; ++n)
                #pragma unroll
                for (int r = 0; r < 4; ++r) {
                    const int row = ib + (l >> 4) * 4 + r;
                    const int idx = (row * 64 + n * 16 + lr) ^ ((row & 7) << 3);
                    PsX[idx] = f2bf(e[n][r]);
                }
            if (lr == 0) {
                #pragma unroll
                for (int r = 0; r < 4; ++r)
                    scX[ib + (l >> 4) * 4 + r] = scr[r];
            }
            const ull ba = __ballot(upd);
            if (l == 0) flX[wid] = (ba != 0ull) ? 1 : 0;
        };

        // preloop: tile 0 -> buf0; prefetch K(1) into B.
        LOADK(khA, klA, 0);
        QKSTEP(khA, klA, Ps0, sc0, fl0);
        LOADK(khB, klB, 1);
        __syncthreads();                                  // [1]

        for (int jt2 = 0; jt2 < 32; jt2 += 2) {
            // iter jt2: compute tile jt2+1 (odd -> buf1) with B; prefetch A=K(jt2+2)
            {
                const int tp = jt2 + 1;
                if (tp < 32) {
                    if (jt2 + 2 < 32) LOADK(khA, klA, jt2 + 2);
                    QKSTEP(khB, klB, Ps1, sc1, fl1);
                }
                __syncthreads();                          // [2 + jt2]
            }
            // iter jt2+1: compute tile jt2+2 (even -> buf0) with A; prefetch B=K(jt2+3)
            {
                const int tp = jt2 + 2;
                if (tp < 32) {
                    if (jt2 + 3 < 32) LOADK(khB, klB, jt2 + 3);
                    QKSTEP(khA, klA, Ps0, sc0, fl0);
                }
                __syncthreads();                          // [3 + jt2]
            }
        }
        if (lr == 0) {
            #pragma unroll
            for (int r = 0; r < 4; ++r)
                l_lds[ib + (l >> 4) * 4 + r] = lrun[r];
        }
        __syncthreads();                                  // [34]
    } else {
        // ======================= CONSUMERS =======================
        const int c0w = (wid - 4) * 128;
        const ushort* vbase = vb + ((size_t)b * C_ + c0w) * W_;

        f32x4 acc[8][4];
        #pragma unroll
        for (int fc = 0; fc < 8; ++fc)
            #pragma unroll
            for (int fi = 0; fi < 4; ++fi) acc[fc][fi] = (f32x4){0.f, 0.f, 0.f, 0.f};

        // jt-invariant P fragment LDS indices (proven swizzle path).
        int pidx[2][4];
        #pragma unroll
        for (int kc = 0; kc < 2; ++kc)
            #pragma unroll
            for (int fi = 0; fi < 4; ++fi) {
                const int row = fi * 16 + lr;
                pidx[kc][fi] = ((row * 64) + kc * 32 + lkb) ^ ((row & 7) << 3);
            }

        short8 vpre[8];   // kc0 V frags for current jt (prefetched)
        #pragma unroll
        for (int fc = 0; fc < 8; ++fc)
            vpre[fc] = *reinterpret_cast<const short8*>(vbase + (size_t)(fc * 16 + lr) * W_ + 0 + lkb);
        __syncthreads();                                  // [1]

        auto CONSUME = [&](const ushort* PsX, const float* scX, const int* flX, int jt) {
            const int j0 = jt * 64;
            // issue kc1 loads now (hidden under flag/rescale + kc0 MFMAs)
            short8 vk1[8];
            #pragma unroll
            for (int fc = 0; fc < 8; ++fc)
                vk1[fc] = *reinterpret_cast<const short8*>(vbase + (size_t)(fc * 16 + lr) * W_ + j0 + 32 + lkb);
            const bool dor = (flX[0] | flX[1] | flX[2] | flX[3]) != 0;
            if (dor) {
                float s4[4];
                #pragma unroll
                for (int fi = 0; fi < 4; ++fi) s4[fi] = scX[fi * 16 + lr];
                #pragma unroll
                for (int fc = 0; fc < 8; ++fc)
                    #pragma unroll
                    for (int fi = 0; fi < 4; ++fi)
                        acc[fc][fi] *= s4[fi];
            }
            short8 p0[4], p1[4];
            #pragma unroll
            for (int fi = 0; fi < 4; ++fi)
                p0[fi] = *reinterpret_cast<const short8*>(&PsX[pidx[0][fi]]);
            #pragma unroll
            for (int fc = 0; fc < 8; ++fc)
                #pragma unroll
                for (int fi = 0; fi < 4; ++fi)
                    acc[fc][fi] = __builtin_amdgcn_mfma_f32_16x16x32_bf16(vpre[fc], p0[fi], acc[fc][fi], 0, 0, 0);
            #pragma unroll
            for (int fi = 0; fi < 4; ++fi)
                p1[fi] = *reinterpret_cast<const short8*>(&PsX[pidx[1][fi]]);
            #pragma unroll
            for (int fc = 0; fc < 8; ++fc)
                #pragma unroll
                for (int fi = 0; fi < 4; ++fi)
                    acc[fc][fi] = __builtin_amdgcn_mfma_f32_16x16x32_bf16(vk1[fc], p1[fi], acc[fc][fi], 0, 0, 0);
            // prefetch next jt's kc0 frags (latency crosses the barrier)
            if (jt + 1 < 32) {
                #pragma unroll
                for (int fc = 0; fc < 8; ++fc)
                    vpre[fc] = *reinterpret_cast<const short8*>(vbase + (size_t)(fc * 16 + lr) * W_ + j0 + 64 + lkb);
            }
        };

        for (int jt2 = 0; jt2 < 32; jt2 += 2) {
            CONSUME(Ps0, sc0, fl0, jt2);
            __syncthreads();                              // [2 + jt2]
            CONSUME(Ps1, sc1, fl1, jt2 + 1);
            __syncthreads();                              // [3 + jt2]
        }
        __syncthreads();                                  // [34] (l_lds published)

        float linv[4];
        #pragma unroll
        for (int fi = 0; fi < 4; ++fi) linv[fi] = 1.0f / l_lds[fi * 16 + lr];

        const float g = gamma[0];
        #pragma unroll
        for (int fc = 0; fc < 8; ++fc) {
            const int c = c0w + fc * 16 + (l >> 4) * 4;
            #pragma unroll
            for (int fi = 0; fi < 4; ++fi) {
                const int icol = i0 + fi * 16 + lr;
                #pragma unroll
                for (int r = 0; r < 4; ++r) {
                    const size_t addr = ((size_t)b * C_ + c + r) * W_ + icol;
                    out[addr] = g * acc[fc][fi][r] * linv[fi] + x[addr];
                }
            }
        }
    }
}

// ---------------------------------------------------------------------------
extern "C" void kernel_launch(void* const* d_in, const int* in_sizes, int n_in,
                              void* d_out, int out_size, void* d_ws, size_t ws_size,
                              hipStream_t stream)
{
    const float* x     = (const float*)d_in[0];
    const float* Wq    = (const float*)d_in[1];
    const float* bq    = (const float*)d_in[2];
    const float* Wk    = (const float*)d_in[3];
    const float* bk    = (const float*)d_in[4];
    const float* Wv    = (const float*)d_in[5];
    const float* bv    = (const float*)d_in[6];
    const float* gamma = (const float*)d_in[7];
    float* out = (float*)d_out;
    float* ws  = (float*)d_ws;

    ushort* vbf = (ushort*)(ws + OFF_VB);
    ushort* qth = (ushort*)(ws + OFF_QTH);
    ushort* qtl = (ushort*)(ws + OFF_QTL);
    ushort* kth = (ushort*)(ws + OFF_KTH);
    ushort* ktl = (ushort*)(ws + OFF_KTL);
    ushort* xth = (ushort*)(ws + OFF_XTH);
    ushort* xtl = (ushort*)(ws + OFF_XTL);
    ushort* wh  = (ushort*)(ws + OFF_WH);
    ushort* wl  = (ushort*)(ws + OFF_WL);

    hipLaunchKernelGGL(k_wsplit, dim3(NROW * C_ / 1024, 1, 1), dim3(256), 0, stream,
                       Wq, Wk, Wv, wh, wl);
    hipLaunchKernelGGL(k_xt,     dim3(W_ / 64, C_ / 64, B_), dim3(256), 0, stream,
                       x, xth, xtl);
    hipLaunchKernelGGL(k_projm,  dim3(W_ / 64, B_, 1), dim3(512), 0, stream,
                       wh, wl, xth, xtl, bq, bk, bv, qth, qtl, kth, ktl, vbf);
    hipLaunchKernelGGL(k_flash,  dim3(W_ / 64 * B_, 1, 1), dim3(512), 0, stream,
                       qth, qtl, kth, ktl, vbf, x, gamma, out);
}